// Round 11
// baseline (398.589 us; speedup 1.0000x reference)
//
#include <hip/hip_runtime.h>
#include <hip/hip_cooperative_groups.h>
#include <stdint.h>

namespace cg = cooperative_groups;

typedef __bf16 bf16;
typedef __attribute__((ext_vector_type(2))) __bf16 bf16x2;
typedef __attribute__((ext_vector_type(4))) __bf16 bf16x4;
typedef __attribute__((ext_vector_type(8))) __bf16 bf16x8;
typedef __attribute__((ext_vector_type(4))) float f32x4;
typedef __attribute__((ext_vector_type(4))) short s16x4;

#define B_  2
#define S_  2048
#define H_  1024
#define NH_ 16
#define HD_ 64
#define QSCL_ (0.125f * 1.44269504f)   // (1/sqrt(64)) * log2(e)

// async 16B global->LDS. LDS dest = wave-uniform base + lane*16.
__device__ __forceinline__ void glds16(const bf16* g, bf16* l) {
  __builtin_amdgcn_global_load_lds(
      (const __attribute__((address_space(1))) uint32_t*)g,
      (__attribute__((address_space(3))) uint32_t*)l, 16, 0, 0);
}

// PV MFMA: 16x16x16 bf16 — B operand layout (k=quad*4+e, col=l15) matches the
// S^T MFMA D layout exactly, so softmax P registers feed it with NO relayout.
__device__ __forceinline__ f32x4 pv_mfma(bf16x4 a, bf16x4 b, f32x4 c) {
#if __has_builtin(__builtin_amdgcn_mfma_f32_16x16x16bf16_1k)
  union U { bf16x4 h; s16x4 s; };
  U ua; ua.h = a;
  U ub; ub.h = b;
  return __builtin_amdgcn_mfma_f32_16x16x16bf16_1k(ua.s, ub.s, c, 0, 0, 0);
#else
  f32x4 d;
  asm volatile("v_mfma_f32_16x16x16_bf16 %0, %1, %2, %3\n\ts_nop 7\n\ts_nop 7"
               : "=v"(d) : "v"(a), "v"(b), "v"(c));
  return d;
#endif
}

// 8 f32 -> bf16x8 (RNE — identical numerics to the original cvt kernel)
__device__ __forceinline__ bf16x8 cvt8(const float4 a, const float4 b) {
  bf16x8 o;
  o[0] = (bf16)a.x; o[1] = (bf16)a.y; o[2] = (bf16)a.z; o[3] = (bf16)a.w;
  o[4] = (bf16)b.x; o[5] = (bf16)b.y; o[6] = (bf16)b.z; o[7] = (bf16)b.w;
  return o;
}

// ===========================================================================
// Phase bodies as device functions (shared by the mega-kernel and the
// fallback 4-dispatch pipeline).  All are the PROVEN R10 kernels, with LDS
// passed as a pointer into a per-kernel union buffer.
// ===========================================================================

// ---- cvt phase: 131072 threads, hs = 4 chunks/thread, each W = 1 chunk ----
__device__ __forceinline__ void cvt_phase(
    int blk, int tid,
    const float* __restrict__ hs, const float* __restrict__ Wq,
    const float* __restrict__ Wk, const float* __restrict__ Wv,
    const float* __restrict__ Wo,
    bf16* __restrict__ hsb, bf16* __restrict__ Wqb, bf16* __restrict__ Wkb,
    bf16* __restrict__ Wvb, bf16* __restrict__ Wob)
{
  const int g = blk * 256 + tid;           // 0..131071
#pragma unroll
  for (int j = 0; j < 4; ++j) {
    const size_t i = ((size_t)g + (size_t)j * 131072) * 8;
    float4 a = *(const float4*)(hs + i), b = *(const float4*)(hs + i + 4);
    *(bf16x8*)(hsb + i) = cvt8(a, b);
  }
  const size_t i = (size_t)g * 8;
  { float4 a = *(const float4*)(Wq + i), b = *(const float4*)(Wq + i + 4);
    *(bf16x8*)(Wqb + i) = cvt8(a, b); }
  { float4 a = *(const float4*)(Wk + i), b = *(const float4*)(Wk + i + 4);
    *(bf16x8*)(Wkb + i) = cvt8(a, b); }
  { float4 a = *(const float4*)(Wv + i), b = *(const float4*)(Wv + i + 4);
    *(bf16x8*)(Wvb + i) = cvt8(a, b); }
  { float4 a = *(const float4*)(Wo + i), b = *(const float4*)(Wo + i + 4);
    *(bf16x8*)(Wob + i) = cvt8(a, b); }
}

// ---- QKV tile (proven m97 128x128xBK32 body).  SM usage: 16384 bf16
//      (As = SM[0..8191] as [2][4096], Bs = SM[8192..16383]). ----
__device__ __forceinline__ void qkv_tile(
    int z, int by, int bx, int tid, bf16* __restrict__ SM,
    const bf16* __restrict__ X,
    const bf16* __restrict__ W0, const bf16* __restrict__ W1, const bf16* __restrict__ W2,
    const float* __restrict__ b0, const float* __restrict__ b1, const float* __restrict__ b2,
    bf16* __restrict__ Y0, bf16* __restrict__ Y1, bf16* __restrict__ Y2)
{
  constexpr int K = 1024, N = 1024;
  const bf16* W; const float* bias; bf16* Y; float ysc;
  if (z == 0)      { W = W0; bias = b0; Y = Y0; ysc = QSCL_; }
  else if (z == 1) { W = W1; bias = b1; Y = Y1; ysc = 1.0f; }
  else             { W = W2; bias = b2; Y = Y2; ysc = 1.0f; }

  const int lane = tid & 63, wave = tid >> 6;
  const int m0 = by * 128, n0 = bx * 128;
  const int wm = (wave >> 1) * 64, wn = (wave & 1) * 64;
  const int r0 = tid >> 2,         c0 = (tid & 3) * 8;
  const int r1 = (256 + tid) >> 2, c1 = ((256 + tid) & 3) * 8;
  const int cb0 = (wave * 64) * 8, cb1 = (256 + wave * 64) * 8;

  bf16* As = SM;          // [2][4096]
  bf16* Bs = SM + 8192;   // [2][4096]

  f32x4 acc[4][4] = {};

  __syncthreads();        // protect buf0 against previous-tile LDS stragglers
  glds16(X + (size_t)(m0 + r0) * K + c0, As + cb0);
  glds16(W + (size_t)(n0 + r0) * K + c0, Bs + cb0);
  glds16(X + (size_t)(m0 + r1) * K + c1, As + cb1);
  glds16(W + (size_t)(n0 + r1) * K + c1, Bs + cb1);

  int pb = 0;
  for (int k0 = 0; k0 < K; k0 += 32, pb ^= 1) {
    __syncthreads();
    if (k0 + 32 < K) {
      const int kn = k0 + 32;
      bf16* An = As + (pb ^ 1) * 4096;
      bf16* Bn = Bs + (pb ^ 1) * 4096;
      glds16(X + (size_t)(m0 + r0) * K + kn + c0, An + cb0);
      glds16(W + (size_t)(n0 + r0) * K + kn + c0, Bn + cb0);
      glds16(X + (size_t)(m0 + r1) * K + kn + c1, An + cb1);
      glds16(W + (size_t)(n0 + r1) * K + kn + c1, Bn + cb1);
    }
    const bf16* Ac = As + pb * 4096;
    const bf16* Bc = Bs + pb * 4096;
    bf16x8 a[4], b[4];
#pragma unroll
    for (int j = 0; j < 4; ++j)
      a[j] = *(const bf16x8*)&Ac[(wm + j * 16 + (lane & 15)) * 32 + (lane >> 4) * 8];
#pragma unroll
    for (int j = 0; j < 4; ++j)
      b[j] = *(const bf16x8*)&Bc[(wn + j * 16 + (lane & 15)) * 32 + (lane >> 4) * 8];
#pragma unroll
    for (int mi = 0; mi < 4; ++mi)
#pragma unroll
      for (int ni = 0; ni < 4; ++ni)
        acc[mi][ni] = __builtin_amdgcn_mfma_f32_16x16x32_bf16(a[mi], b[ni], acc[mi][ni], 0, 0, 0);
  }

#pragma unroll
  for (int mi = 0; mi < 4; ++mi) {
    const int row = m0 + wm + mi * 16 + (lane >> 4) * 4;
#pragma unroll
    for (int ni = 0; ni < 4; ++ni) {
      const int col = n0 + wn + ni * 16 + (lane & 15);
      const float bv = bias[col];
#pragma unroll
      for (int r = 0; r < 4; ++r)
        Y[(size_t)(row + r) * N + col] = (bf16)((acc[mi][ni][r] + bv) * ysc);
    }
  }
}

// ---- O-proj tile (proven R10 64x128xBK32 body).  SM usage: 12288 bf16
//      (As = SM[0..4095] as [2][2048], Bs = SM[4096..12287] as [2][4096]) ----
__device__ __forceinline__ void o_tile(
    int t, int tid, bf16* __restrict__ SM,
    const bf16* __restrict__ X, const bf16* __restrict__ W,
    const float* __restrict__ bias, float* __restrict__ Y)
{
  constexpr int K = 1024, N = 1024;
  const int lane = tid & 63, wave = tid >> 6;
  const int m0 = (t >> 3) * 64;
  const int n0 = (t & 7) * 128;
  const int wm = (wave >> 1) * 32, wn = (wave & 1) * 64;
  const int ar = tid >> 2,  ac = (tid & 3) * 8;
  const int br0 = tid >> 2,          bc0 = (tid & 3) * 8;
  const int br1 = (256 + tid) >> 2,  bc1 = ((256 + tid) & 3) * 8;
  const int acb  = (wave * 64) * 8;
  const int bcb0 = (wave * 64) * 8;
  const int bcb1 = (256 + wave * 64) * 8;

  bf16* As = SM;          // [2][2048]
  bf16* Bs = SM + 4096;   // [2][4096]

  f32x4 acc[2][4] = {};

  __syncthreads();
  glds16(X + (size_t)(m0 + ar) * K + ac,   As + acb);
  glds16(W + (size_t)(n0 + br0) * K + bc0, Bs + bcb0);
  glds16(W + (size_t)(n0 + br1) * K + bc1, Bs + bcb1);

  int pb = 0;
  for (int k0 = 0; k0 < K; k0 += 32, pb ^= 1) {
    __syncthreads();
    if (k0 + 32 < K) {
      const int kn = k0 + 32;
      bf16* An = As + (pb ^ 1) * 2048;
      bf16* Bn = Bs + (pb ^ 1) * 4096;
      glds16(X + (size_t)(m0 + ar) * K + kn + ac,   An + acb);
      glds16(W + (size_t)(n0 + br0) * K + kn + bc0, Bn + bcb0);
      glds16(W + (size_t)(n0 + br1) * K + kn + bc1, Bn + bcb1);
    }
    const bf16* Ac = As + pb * 2048;
    const bf16* Bc = Bs + pb * 4096;
    bf16x8 a[2], b[4];
#pragma unroll
    for (int j = 0; j < 2; ++j)
      a[j] = *(const bf16x8*)&Ac[(wm + j * 16 + (lane & 15)) * 32 + (lane >> 4) * 8];
#pragma unroll
    for (int j = 0; j < 4; ++j)
      b[j] = *(const bf16x8*)&Bc[(wn + j * 16 + (lane & 15)) * 32 + (lane >> 4) * 8];
#pragma unroll
    for (int mi = 0; mi < 2; ++mi)
#pragma unroll
      for (int ni = 0; ni < 4; ++ni)
        acc[mi][ni] = __builtin_amdgcn_mfma_f32_16x16x32_bf16(a[mi], b[ni], acc[mi][ni], 0, 0, 0);
  }

#pragma unroll
  for (int mi = 0; mi < 2; ++mi) {
    const int row = m0 + wm + mi * 16 + (lane >> 4) * 4;
#pragma unroll
    for (int ni = 0; ni < 4; ++ni) {
      const int col = n0 + wn + ni * 16 + (lane & 15);
      const float bv = bias[col];
#pragma unroll
      for (int r = 0; r < 4; ++r)
        Y[(size_t)(row + r) * N + col] = acc[mi][ni][r] + bv;
    }
  }
}

// ---- attn (proven R3 body).  SM usage: 32768 bf16 = 64 KiB
//      (Ks = SM[0..16383] as [2][8192], Vt = SM[16384..32767]) ----
__device__ __forceinline__ void attn_tile_step(
    const bf16* Ksb, const bf16* Vtb, const bf16x8 bq[2], int qrow, int k0,
    bool maskit, float& mr, float& lr, f32x4 oacc[4], int l15, int quad)
{
  // ---- S^T = K Q^T ----
  f32x4 sacc[8] = {};
  __builtin_amdgcn_s_setprio(1);
#pragma unroll
  for (int ks = 0; ks < 2; ++ks) {
#pragma unroll
    for (int mb = 0; mb < 8; ++mb) {
      const int row = mb * 16 + l15;
      const int ch  = (ks * 4 + quad) ^ (l15 & 7);   // XOR de-swizzle
      bf16x8 ak = *(const bf16x8*)&Ksb[row * 64 + ch * 8];
      sacc[mb] = __builtin_amdgcn_mfma_f32_16x16x32_bf16(ak, bq[ks], sacc[mb], 0, 0, 0);
    }
  }
  __builtin_amdgcn_s_setprio(0);

  if (maskit) {
#pragma unroll
    for (int mb = 0; mb < 8; ++mb) {
      const int kb = k0 + mb * 16 + quad * 4;
#pragma unroll
      for (int r = 0; r < 4; ++r)
        if (kb + r > qrow) sacc[mb][r] = -1e30f;
    }
  }

  // max tree + shuffles — runs in PARALLEL with the exp2/PV chain below
  float mx = -1e30f;
#pragma unroll
  for (int mb = 0; mb < 8; ++mb)
    mx = fmaxf(mx, fmaxf(fmaxf(sacc[mb][0], sacc[mb][1]),
                         fmaxf(sacc[mb][2], sacc[mb][3])));
  mx = fmaxf(mx, __shfl_xor(mx, 16, 64));
  mx = fmaxf(mx, __shfl_xor(mx, 32, 64));

  // speculative exp2 with CURRENT mr
  float sum = 0.0f;
  bf16x4 pwv[8];
#pragma unroll
  for (int mb = 0; mb < 8; ++mb) {
    bf16x4 pw;
#pragma unroll
    for (int r = 0; r < 4; ++r) {
      const float p = __builtin_amdgcn_exp2f(sacc[mb][r] - mr);
      sum += p;
      pw[r] = (bf16)p;
    }
    pwv[mb] = pw;
  }
  sum += __shfl_xor(sum, 16, 64);
  sum += __shfl_xor(sum, 32, 64);

  // ---- O^T += V^T P^T ----
  __builtin_amdgcn_s_setprio(1);
#pragma unroll
  for (int mb = 0; mb < 8; ++mb) {
#pragma unroll
    for (int db = 0; db < 4; ++db) {
      const int vch = ((mb * 4 + quad) ^ (l15 & 7)) * 4;
      bf16x4 av = *(const bf16x4*)&Vtb[(db * 16 + l15) * 128 + vch];
      oacc[db] = pv_mfma(av, pwv[mb], oacc[db]);
    }
  }
  __builtin_amdgcn_s_setprio(0);

  lr += sum;
  if (!__all(mx <= mr + 8.0f)) {     // rare fixup (exact algebra, post-PV)
    const float mnew  = fmaxf(mr, mx);
    const float alpha = __builtin_amdgcn_exp2f(mr - mnew);
    lr *= alpha;
#pragma unroll
    for (int db = 0; db < 4; ++db)
#pragma unroll
      for (int r = 0; r < 4; ++r) oacc[db][r] *= alpha;
    mr = mnew;
  }
}

__device__ __forceinline__ void attn_block(
    int lin, int tid, bf16* __restrict__ SM,
    const bf16* __restrict__ Q, const bf16* __restrict__ K,
    const bf16* __restrict__ V, bf16* __restrict__ O)
{
  const int slot = lin >> 3;
  const int bh   = (lin & 7) * 4 + (slot >> 4);
  const int pair = slot & 15;
  const int b    = bh >> 4;
  const int h    = bh & 15;

  const int lane = tid & 63, wave = tid >> 6, quad = lane >> 4, l15 = lane & 15;
  const size_t headoff = (size_t)b * S_ * H_ + (size_t)h * HD_;
  const bf16* Kp = K + headoff;
  const bf16* Vp = V + headoff;

  bf16* Ks = SM;            // [2][8192]
  bf16* Vt = SM + 16384;    // [2][8192]

  const int qlo = pair, qhi = 31 - pair;
  const int nl  = (qlo >> 1) + 1;
  const int nh  = (qhi >> 1) + 1;
  const int qrowL = qlo * 64 + wave * 16 + l15;
  const int qrowH = qhi * 64 + wave * 16 + l15;

  bf16x8 bqL[2], bqH[2];
  bqL[0] = *(const bf16x8*)(Q + headoff + (size_t)qrowL * H_ + quad * 8);
  bqL[1] = *(const bf16x8*)(Q + headoff + (size_t)qrowL * H_ + 32 + quad * 8);
  bqH[0] = *(const bf16x8*)(Q + headoff + (size_t)qrowH * H_ + quad * 8);
  bqH[1] = *(const bf16x8*)(Q + headoff + (size_t)qrowH * H_ + 32 + quad * 8);

  const int vr = lane * 2;
  const int vc = wave * 16;

#define STAGE_K(k0_, buf_)                                                  \
  {                                                                         \
    _Pragma("unroll")                                                       \
    for (int j = 0; j < 4; ++j) {                                           \
      const int n = j * 256 + tid;                                          \
      const int row = n >> 3;                                               \
      const int cg  = (n & 7) ^ (row & 7);                                  \
      glds16(Kp + (size_t)((k0_) + row) * H_ + cg * 8,                      \
             Ks + (buf_) * 8192 + (j * 256 + wave * 64) * 8);               \
    }                                                                       \
  }

#define LOAD_V(k0_)                                                         \
  {                                                                         \
    vreg[0] = *(const bf16x8*)(Vp + (size_t)((k0_) + vr) * H_ + vc);        \
    vreg[1] = *(const bf16x8*)(Vp + (size_t)((k0_) + vr) * H_ + vc + 8);    \
    vreg[2] = *(const bf16x8*)(Vp + (size_t)((k0_) + vr + 1) * H_ + vc);    \
    vreg[3] = *(const bf16x8*)(Vp + (size_t)((k0_) + vr + 1) * H_ + vc + 8);\
  }

#define WRITE_V(buf_)                                                       \
  {                                                                         \
    _Pragma("unroll")                                                       \
    for (int e = 0; e < 8; ++e) {                                           \
      const int sw = (((vr >> 2) ^ e) * 4) + (vr & 3);                      \
      bf16x2 p0; p0[0] = vreg[0][e]; p0[1] = vreg[2][e];                    \
      *(bf16x2*)&Vt[(buf_) * 8192 + (vc + e) * 128 + sw] = p0;              \
      bf16x2 p1; p1[0] = vreg[1][e]; p1[1] = vreg[3][e];                    \
      *(bf16x2*)&Vt[(buf_) * 8192 + (vc + 8 + e) * 128 + sw] = p1;          \
    }                                                                       \
  }

  bf16x8 vreg[4];

  STAGE_K(0, 0);
  LOAD_V(0);
  WRITE_V(0);
  __syncthreads();

  float mrL = 0.0f, lrL = 0.0f, mrH = 0.0f, lrH = 0.0f;
  f32x4 oL[4] = {}, oH[4] = {};

  for (int it = 0; it < nh; ++it) {
    const int c = it & 1;
    const bool pre = (it + 1 < nh);

    if (pre) {
      STAGE_K((it + 1) * 128, c ^ 1);
      LOAD_V((it + 1) * 128);
    }

    attn_tile_step(Ks + c * 8192, Vt + c * 8192, bqH, qrowH, it * 128,
                   it == nh - 1, mrH, lrH, oH, l15, quad);
    if (it < nl)
      attn_tile_step(Ks + c * 8192, Vt + c * 8192, bqL, qrowL, it * 128,
                     it == nl - 1, mrL, lrL, oL, l15, quad);

    if (pre) {
      WRITE_V(c ^ 1);
      __syncthreads();
    }
  }

  const float invL = 1.0f / lrL;
#pragma unroll
  for (int db = 0; db < 4; ++db) {
    bf16x4 o;
#pragma unroll
    for (int r = 0; r < 4; ++r) o[r] = (bf16)(oL[db][r] * invL);
    *(bf16x4*)(O + headoff + (size_t)qrowL * H_ + db * 16 + quad * 4) = o;
  }
  const float invH = 1.0f / lrH;
#pragma unroll
  for (int db = 0; db < 4; ++db) {
    bf16x4 o;
#pragma unroll
    for (int r = 0; r < 4; ++r) o[r] = (bf16)(oH[db][r] * invH);
    *(bf16x4*)(O + headoff + (size_t)qrowH * H_ + db * 16 + quad * 4) = o;
  }
#undef STAGE_K
#undef LOAD_V
#undef WRITE_V
}

// ===========================================================================
// Mega-kernel: all 4 phases, one cooperative launch, grid 512 x 256 =
// exactly 2 blocks/CU (LDS 64 KiB).  grid.sync() between phases replaces
// 3 dispatch boundaries (~20 us each per the R0-R10 budget invariant).
// ===========================================================================
__global__ __launch_bounds__(256, 2) void mega(
    const float* __restrict__ hs,
    const float* __restrict__ Wq, const float* __restrict__ Wk,
    const float* __restrict__ Wv, const float* __restrict__ Wo,
    const float* __restrict__ bq, const float* __restrict__ bk,
    const float* __restrict__ bv, const float* __restrict__ bo,
    float* __restrict__ out, bf16* __restrict__ ws)
{
  __shared__ __align__(16) bf16 SM[32768];   // 64 KiB, phase-unioned
  cg::grid_group grid = cg::this_grid();

  const size_t elems = (size_t)B_ * S_ * H_;   // 4,194,304
  const size_t wel   = (size_t)H_ * H_;        // 1,048,576
  bf16* hsb = ws;               // phase-1 out, phase-2 in
  bf16* AO  = ws;               // phase-3 out (hsb dead), phase-4 in
  bf16* Wqb = ws + elems;
  bf16* Wkb = Wqb + wel;
  bf16* Wvb = Wkb + wel;
  bf16* Wob = Wvb + wel;
  bf16* Qw  = Wob + wel;
  bf16* Kw  = Qw + elems;
  bf16* Vw  = Kw + elems;

  const int tid = threadIdx.x;
  const int blk = blockIdx.x;

  // phase 1: fp32 -> bf16
  cvt_phase(blk, tid, hs, Wq, Wk, Wv, Wo, hsb, Wqb, Wkb, Wvb, Wob);
  grid.sync();

  // phase 2: QKV GEMM — 768 tiles on 512 blocks (blocks <256 do 2)
  for (int t = blk; t < 768; t += 512) {
    const int z = t >> 8, r = t & 255;
    qkv_tile(z, r >> 3, r & 7, tid, SM, hsb, Wqb, Wkb, Wvb,
             bq, bk, bv, Qw, Kw, Vw);
  }
  grid.sync();

  // phase 3: attention (512 blocks, exact fit)
  attn_block(blk, tid, SM, Qw, Kw, Vw, AO);
  grid.sync();

  // phase 4: O-projection — 512 tiles of 64x128, 1 per block
  o_tile(blk, tid, SM, AO, Wob, bo, out);
}

// ===========================================================================
// Fallback 4-dispatch pipeline (thin wrappers over the same device fns) —
// used only if cooperative launch is unavailable.
// ===========================================================================
__global__ __launch_bounds__(256) void k_cvt(
    const float* __restrict__ hs, const float* __restrict__ Wq,
    const float* __restrict__ Wk, const float* __restrict__ Wv,
    const float* __restrict__ Wo, bf16* __restrict__ ws)
{
  const size_t elems = (size_t)B_ * S_ * H_;
  const size_t wel   = (size_t)H_ * H_;
  bf16* hsb = ws;
  bf16* Wqb = ws + elems;
  bf16* Wkb = Wqb + wel;
  bf16* Wvb = Wkb + wel;
  bf16* Wob = Wvb + wel;
  cvt_phase(blockIdx.x, threadIdx.x, hs, Wq, Wk, Wv, Wo, hsb, Wqb, Wkb, Wvb, Wob);
}

__global__ __launch_bounds__(256) void k_qkv(
    const bf16* __restrict__ X,
    const bf16* __restrict__ W0, const bf16* __restrict__ W1, const bf16* __restrict__ W2,
    const float* __restrict__ b0, const float* __restrict__ b1, const float* __restrict__ b2,
    bf16* __restrict__ Y0, bf16* __restrict__ Y1, bf16* __restrict__ Y2)
{
  __shared__ __align__(16) bf16 SM[16384];
  const int t = blockIdx.x;
  qkv_tile(t >> 8, (t & 255) >> 3, t & 7, threadIdx.x, SM,
           X, W0, W1, W2, b0, b1, b2, Y0, Y1, Y2);
}

__global__ __launch_bounds__(256, 2) void k_attn(
    const bf16* __restrict__ Q, const bf16* __restrict__ K,
    const bf16* __restrict__ V, bf16* __restrict__ O)
{
  __shared__ __align__(16) bf16 SM[32768];
  attn_block(blockIdx.x, threadIdx.x, SM, Q, K, V, O);
}

__global__ __launch_bounds__(256) void k_o(
    const bf16* __restrict__ X, const bf16* __restrict__ W,
    const float* __restrict__ bias, float* __restrict__ Y)
{
  __shared__ __align__(16) bf16 SM[12288];
  o_tile(blockIdx.x, threadIdx.x, SM, X, W, bias, Y);
}

extern "C" void kernel_launch(void* const* d_in, const int* in_sizes, int n_in,
                              void* d_out, int out_size, void* d_ws, size_t ws_size,
                              hipStream_t stream) {
  const float* hs = (const float*)d_in[0];
  const float* Wq = (const float*)d_in[1]; const float* bq = (const float*)d_in[2];
  const float* Wk = (const float*)d_in[3]; const float* bk = (const float*)d_in[4];
  const float* Wv = (const float*)d_in[5]; const float* bv = (const float*)d_in[6];
  const float* Wo = (const float*)d_in[7]; const float* bo = (const float*)d_in[8];
  float* out = (float*)d_out;
  bf16* ws = (bf16*)d_ws;

  void* args[] = {(void*)&hs, (void*)&Wq, (void*)&Wk, (void*)&Wv, (void*)&Wo,
                  (void*)&bq, (void*)&bk, (void*)&bv, (void*)&bo,
                  (void*)&out, (void*)&ws};

  if (hipLaunchCooperativeKernel((const void*)mega, dim3(512), dim3(256),
                                 args, 0, stream) != hipSuccess) {
    // fallback: proven 4-dispatch pipeline (same device-fn bodies)
    const size_t elems = (size_t)B_ * S_ * H_;
    const size_t wel   = (size_t)H_ * H_;
    bf16* hsb = ws; bf16* AO = ws;
    bf16* Wqb = ws + elems;
    bf16* Wkb = Wqb + wel;
    bf16* Wvb = Wkb + wel;
    bf16* Wob = Wvb + wel;
    bf16* Qw  = Wob + wel;
    bf16* Kw  = Qw + elems;
    bf16* Vw  = Kw + elems;

    k_cvt<<<dim3(512), dim3(256), 0, stream>>>(hs, Wq, Wk, Wv, Wo, ws);
    k_qkv<<<dim3(768), dim3(256), 0, stream>>>(hsb, Wqb, Wkb, Wvb,
                                               bq, bk, bv, Qw, Kw, Vw);
    k_attn<<<dim3(512), dim3(256), 0, stream>>>(Qw, Kw, Vw, AO);
    k_o<<<dim3(512), dim3(256), 0, stream>>>(AO, Wob, bo, out);
  }
}